// Round 4
// baseline (587.953 us; speedup 1.0000x reference)
//
#include <hip/hip_runtime.h>
#include <math.h>

#define B_   8
#define C_   256
#define HW_  4096
#define N_   32768   // B_*HW_
#define M_   2024
#define MP_  2048    // M padded to multiple of 64
#define CH_  64
#define NCHUNK (MP_ / 64)  // 32 memory chunks; chunk 32 = W1^T (gate fusion)
#define INV_TEMP 33.333333333333336f
#define NEPS 1e-12f

typedef __attribute__((ext_vector_type(8))) short short8;   // 8 x bf16 (4 VGPRs)
typedef __attribute__((ext_vector_type(4))) float floatx4;  // MFMA accumulator

__device__ __forceinline__ unsigned short f2bf(float f) {
  union { float f; unsigned u; } v; v.f = f;
  unsigned r = v.u + 0x7FFFu + ((v.u >> 16) & 1u);  // RNE, finite inputs only
  return (unsigned short)(r >> 16);
}
__device__ __forceinline__ float bf2f(unsigned short b) {
  union { unsigned u; float f; } v; v.u = ((unsigned)b) << 16; return v.f;
}

// raw workgroup barrier that does NOT drain vmcnt (keeps global_load_lds
// prefetch in flight across it) — CK/AITER idiom.
__device__ __forceinline__ void barrier_lds_only() {
  asm volatile("s_waitcnt lgkmcnt(0)\n\ts_barrier" ::: "memory");
}

// async 16B/lane global->LDS copy; LDS dest = wave-uniform base + lane*16.
__device__ __forceinline__ void async_copy16(const unsigned short* gsrc,
                                             unsigned short* lds) {
  __builtin_amdgcn_global_load_lds(
      (const __attribute__((address_space(1))) void*)gsrc,
      (__attribute__((address_space(3))) void*)lds, 16, 0, 0);
}

// ---- normalize memory rows -> memS (MFMA B-frag order) + membT [C][MP] ----
// memS element (m, c): unit = ((m>>6)*32 + (c>>5)*4 + ((c>>3)&3))*64 + (m&63),
// u16 index = unit*8 + (c&7). A 64-row chunk is a contiguous 32 KB block that
// the flash kernel copies to LDS verbatim via global_load_lds.
// Blocks 64/65: pack W1^T (row h = w1[:,h], bf16, no normalize) as chunk 32
// of fgS/bgS — the flash kernel computes the gate hidden layer as one extra
// S-phase chunk (gate_kernel eliminated).
__global__ __launch_bounds__(256) void norm_mem_kernel(
    const float* __restrict__ fg, const float* __restrict__ bg,
    const float* __restrict__ w1f, const float* __restrict__ w1b,
    unsigned short* __restrict__ fgS, unsigned short* __restrict__ bgS,
    unsigned short* __restrict__ fgT, unsigned short* __restrict__ bgT) {
  __shared__ unsigned short tile[64][258];
  int bid = blockIdx.x;  // 0..31 fg chunks, 32..63 bg chunks, 64/65 w1 chunks
  int t = threadIdx.x;
  int rr = t >> 2, c4 = t & 3;  // row rr, channel quarter c4

  if (bid >= 64) {  // W1^T chunk (64 rows h, 256 cols c), chunk index 32
    const float* srcw = (bid == 64) ? w1f : w1b;
    unsigned short* ms = (bid == 64) ? fgS : bgS;
#pragma unroll
    for (int i = 0; i < 16; ++i) {
      int c = c4 * 64 + i * 4;
      ushort4 o;
      o.x = f2bf(srcw[(size_t)(c + 0) * CH_ + rr]);
      o.y = f2bf(srcw[(size_t)(c + 1) * CH_ + rr]);
      o.z = f2bf(srcw[(size_t)(c + 2) * CH_ + rr]);
      o.w = f2bf(srcw[(size_t)(c + 3) * CH_ + rr]);
      int unit = (32 * 32 + (c >> 5) * 4 + ((c >> 3) & 3)) * 64 + rr;
      *(ushort4*)&ms[(size_t)unit * 8 + (c & 7)] = o;
    }
    return;  // whole block exits (no __syncthreads reached)
  }

  const float* src; unsigned short *ms, *mt; int r0;
  if (bid < 32) { src = fg; ms = fgS; mt = fgT; r0 = bid * 64; }
  else          { src = bg; ms = bgS; mt = bgT; r0 = (bid - 32) * 64; }
  int row = r0 + rr;
  int chunk = r0 >> 6;
  float v[64];
  float s = 0.f;
  if (row < M_) {
    const float4* p = (const float4*)(src + (size_t)row * C_ + c4 * 64);
#pragma unroll
    for (int i = 0; i < 16; ++i) {
      float4 q = p[i];
      v[i * 4 + 0] = q.x; v[i * 4 + 1] = q.y; v[i * 4 + 2] = q.z; v[i * 4 + 3] = q.w;
      s += q.x * q.x + q.y * q.y + q.z * q.z + q.w * q.w;
    }
  } else {
#pragma unroll
    for (int i = 0; i < 64; ++i) v[i] = 0.f;  // zero padding rows
  }
  s += __shfl_xor(s, 1, 64);
  s += __shfl_xor(s, 2, 64);
  float inv = (row < M_) ? 1.0f / fmaxf(sqrtf(s), NEPS) : 0.f;
#pragma unroll
  for (int i = 0; i < 16; ++i) {
    int c = c4 * 64 + i * 4;
    ushort4 o;
    o.x = f2bf(v[i * 4 + 0] * inv); o.y = f2bf(v[i * 4 + 1] * inv);
    o.z = f2bf(v[i * 4 + 2] * inv); o.w = f2bf(v[i * 4 + 3] * inv);
    int unit = (chunk * 32 + (c >> 5) * 4 + ((c >> 3) & 3)) * 64 + rr;
    *(ushort4*)&ms[(size_t)unit * 8 + (c & 7)] = o;
    *(ushort4*)&tile[rr][c] = o;
  }
  __syncthreads();
  int m = t & 63, cw = t >> 6;
#pragma unroll 8
  for (int j = 0; j < 64; ++j) {
    int c = cw * 64 + j;
    mt[(size_t)c * MP_ + r0 + m] = tile[m][c];
  }
}

// ---- fused per-pixel inv-norm + xnb bf16 [N,C] build (one feats pass) ----
__global__ __launch_bounds__(256) void prep_x_kernel(
    const float* __restrict__ feats, float* __restrict__ invn,
    unsigned short* __restrict__ xnb) {
  __shared__ unsigned short tileb[256][66];
  __shared__ float part[4][64];
  __shared__ float invs[64];
  int t = threadIdx.x, hwl = t & 63, cw = t >> 6;
  int n0 = blockIdx.x * 64;
  int b = n0 >> 12, hw0 = n0 & 4095;
  const float* p = feats + (size_t)b * C_ * HW_ + hw0 + hwl;
  float s = 0.f;
#pragma unroll 8
  for (int i = 0; i < 64; ++i) {
    int c = cw * 64 + i;
    float v = p[(size_t)c * HW_];
    s += v * v;
    tileb[c][hwl] = f2bf(v);
  }
  part[cw][hwl] = s;
  __syncthreads();
  if (t < 64) {
    float tot = part[0][t] + part[1][t] + part[2][t] + part[3][t];
    float inv = 1.0f / fmaxf(sqrtf(tot), NEPS);
    invn[n0 + t] = inv;
    invs[t] = inv;
  }
  __syncthreads();
  int px = t >> 2, q = t & 3;
  float iv = invs[px];
  unsigned short* xp = xnb + (size_t)(n0 + px) * C_;
#pragma unroll
  for (int blk = 0; blk < 8; ++blk) {
    int cb = blk * 4 + q;  // 4 q-lanes -> 64 B contiguous stores
    short8 o;
#pragma unroll
    for (int j = 0; j < 8; ++j)
      o[j] = (short)f2bf(bf2f(tileb[cb * 8 + j][px]) * iv);
    *(short8*)&xp[cb * 8] = o;
  }
}

// stage one 32 KB memS chunk into mtile (contiguous copy, no VGPR round-trip)
__device__ __forceinline__ void stage_chunk(const unsigned short* memS, int mc,
                                            unsigned short* mtile, int w, int l) {
  const unsigned short* src = memS + (size_t)mc * 16384;
#pragma unroll
  for (int it = 0; it < 4; ++it) {
    int seg = (it * 8 + w) * 512;  // u16 units; 64 lanes x 16 B = 1 KB/wave/iter
    async_copy16(src + seg + l * 8, mtile + seg);
  }
}

// ---------------- fused MFMA flash attention v8 ----------------
// = verified v4 structure + gate fusion. Chunk 32 of memS holds W1^T, so
// the gate hidden layer h[px][hid] = xn @ W1 falls out of one extra S-phase
// pass (accS D-layout: px = 16rg+quad*4+r, hid = mh*32+mt2*16+lm). Finish:
// +b1, relu, *w2, lm-shuffle-reduce, cross-wave LDS atomic, sigmoid at comb.
// gate_kernel and the gf/gb global round-trip are eliminated. setprio
// removed (v7: neutral-to-negative in this lockstep schedule); ebias
// exp-mask kept (bit-exact, one less VALU op per P element).
// LDS-bound accounting (per CU-chunk: S 256KB + PV 128KB + writes 80KB
// ≈ 3.7K cyc ≈ 90% of runtime) — duplication cuts are register-infeasible
// at the 128-reg cap (v6 spill), so flash stays at this tiling.
__global__ __launch_bounds__(512, 4) void flash_fused_kernel(
    const unsigned short* __restrict__ xnb,
    const unsigned short* __restrict__ fgS, const unsigned short* __restrict__ fgT,
    const unsigned short* __restrict__ bgS, const unsigned short* __restrict__ bgT,
    const float* __restrict__ feats, const float* __restrict__ invn,
    const float* __restrict__ b1fp, const float* __restrict__ w2fp,
    const float* __restrict__ b2fp, const float* __restrict__ b1bp,
    const float* __restrict__ w2bp, const float* __restrict__ b2bp,
    float* __restrict__ out) {
  __shared__ __align__(16) char smem[49920];
  unsigned short* mtile = (unsigned short*)smem;            // 32 KB frag-order chunk
  unsigned short* Pbuf0 = (unsigned short*)(smem + 32768);  // 8 KB: unit=(g*64+prow)
  unsigned short* Pbuf1 = (unsigned short*)(smem + 40960);  // 8 KB
  float* rowsum = (float*)(smem + 49152);                   // [64]
  float* comb   = (float*)(smem + 49408);                   // [64]
  float* gpart  = (float*)(smem + 49664);                   // [64] gate partials
  float* trans  = (float*)smem;                             // [64][67] f32, aliases mtile

  int t = threadIdx.x;
  int w = t >> 6, l = t & 63;
  int lm = l & 15, quad = l >> 4;
  int rg = w & 3, mh = w >> 2;
  int row0 = blockIdx.x * 64;

  // A-frags: rows row0 + 16*rg + lm (waves rg and rg+4 duplicate)
  short8 afrag[8];
  {
    const unsigned short* ap = xnb + (size_t)(row0 + 16 * rg + lm) * C_ + quad * 8;
#pragma unroll
    for (int kb = 0; kb < 8; ++kb)
      afrag[kb] = *(const short8*)(ap + kb * 32);
  }

  int bb = row0 >> 12, hw0 = row0 & 4095;
  float iv = invn[row0 + l];
  size_t ob = (size_t)bb * (size_t)C_ * HW_ + hw0 + l;

#pragma unroll 1
  for (int pass = 0; pass < 2; ++pass) {
    const unsigned short* memS  = pass ? bgS : fgS;
    const unsigned short* membT = pass ? bgT : fgT;
    const float* b1p = pass ? b1bp : b1fp;
    const float* w2p = pass ? w2bp : w2fp;
    float b2v = (pass ? b2bp : b2fp)[0];

    floatx4 accO[4][2];
#pragma unroll
    for (int rt = 0; rt < 4; ++rt)
#pragma unroll
      for (int ct = 0; ct < 2; ++ct) accO[rt][ct] = (floatx4){0.f, 0.f, 0.f, 0.f};
    float rs[4] = {0.f, 0.f, 0.f, 0.f};
    if (t < 64) { rowsum[t] = 0.f; gpart[t] = 0.f; }  // ordered by chunk barriers

    stage_chunk(memS, 0, mtile, w, l);

#pragma unroll 1
    for (int mc = 0; mc <= NCHUNK; ++mc) {
      __syncthreads();  // A: drains vmcnt -> mtile[mc] ready for all waves
      bool isGate = (mc == NCHUNK);

      // PV B-frags for this chunk (global, read-once; hidden under S-phase)
      short8 bfT[2][2];
      if (!isGate) {
#pragma unroll
        for (int ct = 0; ct < 2; ++ct) {
          const unsigned short* tp =
              membT + (size_t)(w * 32 + ct * 16 + lm) * MP_ + mc * 64 + quad * 8;
          bfT[ct][0] = *(const short8*)(tp);
          bfT[ct][1] = *(const short8*)(tp + 32);
        }
      }

      // ---- S = Q @ mem^T (rows 16rg.., m-half mh) from LDS frag-order tile ----
      floatx4 accS[2];
      accS[0] = (floatx4){0.f, 0.f, 0.f, 0.f};
      accS[1] = (floatx4){0.f, 0.f, 0.f, 0.f};
#pragma unroll
      for (int mt2 = 0; mt2 < 2; ++mt2) {
        int mrow = mh * 32 + mt2 * 16 + lm;
#pragma unroll
        for (int kb = 0; kb < 8; ++kb) {
          short8 bf = *(const short8*)&mtile[(size_t)(((kb * 4 + quad) * 64) + mrow) * 8];
          accS[mt2] = __builtin_amdgcn_mfma_f32_16x16x32_bf16(afrag[kb], bf, accS[mt2], 0, 0, 0);
        }
      }

      if (!isGate) {
        // ---- P = exp(S/T) bf16 (unnormalized; |logit|<=33.3), frag-order ----
        unsigned short* P = (mc & 1) ? Pbuf1 : Pbuf0;
#pragma unroll
        for (int mt2 = 0; mt2 < 2; ++mt2) {
          int m = mh * 32 + mt2 * 16 + lm;
          // exp-mask bias: padding rows get exp(-1e30) = 0 (no select);
          // valid rows: fma(S, IT, 0) == rn(S*IT) — bit-exact.
          float ebias = (mc * 64 + m < M_) ? 0.f : -1e30f;
          int g = mh * 4 + mt2 * 2 + (lm >> 3);
#pragma unroll
          for (int r = 0; r < 4; ++r) {
            float pv = __expf(__builtin_fmaf(accS[mt2][r], INV_TEMP, ebias));
            unsigned short pb = f2bf(pv);
            rs[r] += bf2f(pb);
            P[(g * 64 + 16 * rg + quad * 4 + r) * 8 + (lm & 7)] = pb;
          }
        }
        barrier_lds_only();  // B: P visible + mtile S-reads done (vmcnt alive)

        // issue next chunk's async stage (in flight across PV)
        if (mc + 1 <= NCHUNK) stage_chunk(memS, mc + 1, mtile, w, l);

        // ---- O += P @ mem (this wave's 32-wide C-slice) ----
#pragma unroll
        for (int rt = 0; rt < 4; ++rt) {
          short8 pf0 = *(const short8*)&P[(size_t)((0 + quad) * 64 + rt * 16 + lm) * 8];
          short8 pf1 = *(const short8*)&P[(size_t)((4 + quad) * 64 + rt * 16 + lm) * 8];
#pragma unroll
          for (int ct = 0; ct < 2; ++ct) {
            accO[rt][ct] = __builtin_amdgcn_mfma_f32_16x16x32_bf16(pf0, bfT[ct][0], accO[rt][ct], 0, 0, 0);
            accO[rt][ct] = __builtin_amdgcn_mfma_f32_16x16x32_bf16(pf1, bfT[ct][1], accO[rt][ct], 0, 0, 0);
          }
        }
      } else {
        // ---- gate finish: accS[mt2][r] = h[px=16rg+quad*4+r][hid=mh*32+mt2*16+lm]
        float b1a = b1p[mh * 32 + lm];
        float b1c = b1p[mh * 32 + 16 + lm];
        float w2a = w2p[mh * 32 + lm];
        float w2c = w2p[mh * 32 + 16 + lm];
        float p[4];
#pragma unroll
        for (int r = 0; r < 4; ++r)
          p[r] = fmaxf(accS[0][r] + b1a, 0.f) * w2a +
                 fmaxf(accS[1][r] + b1c, 0.f) * w2c;
#pragma unroll
        for (int off = 1; off < 16; off <<= 1)
#pragma unroll
          for (int r = 0; r < 4; ++r) p[r] += __shfl_xor(p[r], off, 64);
        if (lm == 0) {
#pragma unroll
          for (int r = 0; r < 4; ++r)
            atomicAdd(&gpart[16 * rg + quad * 4 + r], p[r]);
        }
      }
    }

    // ---- rowsum: intra-wave shuffle over lm, cross-wave LDS atomic ----
#pragma unroll
    for (int off = 1; off < 16; off <<= 1)
#pragma unroll
      for (int r = 0; r < 4; ++r) rs[r] += __shfl_xor(rs[r], off, 64);
    if (lm == 0) {
#pragma unroll
      for (int r = 0; r < 4; ++r) atomicAdd(&rowsum[16 * rg + quad * 4 + r], rs[r]);
    }
    __syncthreads();
    if (t < 64) {
      float g = 1.f / (1.f + __expf(-(gpart[t] + b2v)));
      comb[t] = g / rowsum[t];
    }
    __syncthreads();

    // ---- epilogue (trans aliases mtile; no stage loads in flight here) ----
#pragma unroll 1
    for (int cg2 = 0; cg2 < 4; ++cg2) {
      if ((w >> 1) == cg2) {
#pragma unroll
        for (int rt = 0; rt < 4; ++rt)
#pragma unroll
          for (int r = 0; r < 4; ++r) {
            float cf = comb[16 * rt + quad * 4 + r];
#pragma unroll
            for (int ct = 0; ct < 2; ++ct)
              trans[(16 * rt + quad * 4 + r) * 67 + (w & 1) * 32 + ct * 16 + lm] =
                  cf * accO[rt][ct][r];
          }
      }
      __syncthreads();
      if (pass == 0) {
#pragma unroll
        for (int i = 0; i < 8; ++i) {
          int cl = w * 8 + i;
          int cg = cg2 * 64 + cl;
          out[ob + (size_t)cg * HW_] = trans[l * 67 + cl];  // out = alpha_f * O_f
        }
      } else {
#pragma unroll
        for (int i = 0; i < 8; ++i) {
          int cl = w * 8 + i;
          int cg = cg2 * 64 + cl;
          size_t a = ob + (size_t)cg * HW_;
          out[a] = feats[a] * iv + out[a] - trans[l * 67 + cl];
        }
      }
      __syncthreads();
    }
  }
}

extern "C" void kernel_launch(void* const* d_in, const int* in_sizes, int n_in,
                              void* d_out, int out_size, void* d_ws, size_t ws_size,
                              hipStream_t stream) {
  const float* feats = (const float*)d_in[0];
  const float* fg    = (const float*)d_in[1];
  const float* bg    = (const float*)d_in[2];
  const float* w1f   = (const float*)d_in[3];
  const float* b1f   = (const float*)d_in[4];
  const float* w2f   = (const float*)d_in[5];
  const float* b2f   = (const float*)d_in[6];
  const float* w1b   = (const float*)d_in[7];
  const float* b1b   = (const float*)d_in[8];
  const float* w2b   = (const float*)d_in[9];
  const float* b2b   = (const float*)d_in[10];
  float* out = (float*)d_out;

  char* ws = (char*)d_ws;
  unsigned short* xnb = (unsigned short*)ws;                 // N_*C_ bf16
  unsigned short* fgS = xnb + (size_t)N_ * C_;               // (MP_+64)*C_ frag order
  unsigned short* bgS = fgS + (size_t)(MP_ + 64) * C_;       // (chunk 32 = W1^T)
  unsigned short* fgT = bgS + (size_t)(MP_ + 64) * C_;       // C_*MP_
  unsigned short* bgT = fgT + (size_t)C_ * MP_;
  float* invn = (float*)(bgT + (size_t)C_ * MP_);            // N_

  norm_mem_kernel<<<66, 256, 0, stream>>>(fg, bg, w1f, w1b, fgS, bgS, fgT, bgT);
  prep_x_kernel<<<N_ / 64, 256, 0, stream>>>(feats, invn, xnb);
  flash_fused_kernel<<<N_ / 64, 512, 0, stream>>>(
      xnb, fgS, fgT, bgS, bgT, feats, invn,
      b1f, w2f, b2f, b1b, w2b, b2b, out);
}

// Round 5
// 305.853 us; speedup vs baseline: 1.9223x; 1.9223x over previous
//
#include <hip/hip_runtime.h>
#include <math.h>

#define B_   8
#define C_   256
#define HW_  4096
#define N_   32768   // B_*HW_
#define M_   2024
#define MP_  2048    // M padded to multiple of 64
#define CH_  64
#define NCHUNK (MP_ / 64)  // 32 memory chunks; chunk 32 = W1^T (gate fusion)
#define INV_TEMP 33.333333333333336f
#define NEPS 1e-12f

typedef __attribute__((ext_vector_type(8))) short short8;   // 8 x bf16 (4 VGPRs)
typedef __attribute__((ext_vector_type(4))) float floatx4;  // MFMA accumulator

__device__ __forceinline__ unsigned short f2bf(float f) {
  union { float f; unsigned u; } v; v.f = f;
  unsigned r = v.u + 0x7FFFu + ((v.u >> 16) & 1u);  // RNE, finite inputs only
  return (unsigned short)(r >> 16);
}
__device__ __forceinline__ float bf2f(unsigned short b) {
  union { unsigned u; float f; } v; v.u = ((unsigned)b) << 16; return v.f;
}

// raw workgroup barrier that does NOT drain vmcnt (keeps global_load_lds
// prefetch in flight across it) — CK/AITER idiom.
__device__ __forceinline__ void barrier_lds_only() {
  asm volatile("s_waitcnt lgkmcnt(0)\n\ts_barrier" ::: "memory");
}

// async 16B/lane global->LDS copy; LDS dest = wave-uniform base + lane*16.
__device__ __forceinline__ void async_copy16(const unsigned short* gsrc,
                                             unsigned short* lds) {
  __builtin_amdgcn_global_load_lds(
      (const __attribute__((address_space(1))) void*)gsrc,
      (__attribute__((address_space(3))) void*)lds, 16, 0, 0);
}

// ---- normalize memory rows -> memS (MFMA B-frag order) + membT [C][MP] ----
// memS element (m, c): unit = ((m>>6)*32 + (c>>5)*4 + ((c>>3)&3))*64 + (m&63),
// u16 index = unit*8 + (c&7). A 64-row chunk is a contiguous 32 KB block that
// the flash kernel copies to LDS verbatim via global_load_lds.
// Blocks 64/65: pack W1^T (row h = w1[:,h], bf16, no normalize) as chunk 32
// of fgS/bgS — the flash kernel computes the gate hidden layer as a peeled
// extra S-phase pass (gate_kernel eliminated).
__global__ __launch_bounds__(256) void norm_mem_kernel(
    const float* __restrict__ fg, const float* __restrict__ bg,
    const float* __restrict__ w1f, const float* __restrict__ w1b,
    unsigned short* __restrict__ fgS, unsigned short* __restrict__ bgS,
    unsigned short* __restrict__ fgT, unsigned short* __restrict__ bgT) {
  __shared__ unsigned short tile[64][258];
  int bid = blockIdx.x;  // 0..31 fg chunks, 32..63 bg chunks, 64/65 w1 chunks
  int t = threadIdx.x;
  int rr = t >> 2, c4 = t & 3;  // row rr, channel quarter c4

  if (bid >= 64) {  // W1^T chunk (64 rows h, 256 cols c), chunk index 32
    const float* srcw = (bid == 64) ? w1f : w1b;
    unsigned short* ms = (bid == 64) ? fgS : bgS;
#pragma unroll
    for (int i = 0; i < 16; ++i) {
      int c = c4 * 64 + i * 4;
      ushort4 o;
      o.x = f2bf(srcw[(size_t)(c + 0) * CH_ + rr]);
      o.y = f2bf(srcw[(size_t)(c + 1) * CH_ + rr]);
      o.z = f2bf(srcw[(size_t)(c + 2) * CH_ + rr]);
      o.w = f2bf(srcw[(size_t)(c + 3) * CH_ + rr]);
      int unit = (32 * 32 + (c >> 5) * 4 + ((c >> 3) & 3)) * 64 + rr;
      *(ushort4*)&ms[(size_t)unit * 8 + (c & 7)] = o;
    }
    return;  // whole block exits (no __syncthreads reached)
  }

  const float* src; unsigned short *ms, *mt; int r0;
  if (bid < 32) { src = fg; ms = fgS; mt = fgT; r0 = bid * 64; }
  else          { src = bg; ms = bgS; mt = bgT; r0 = (bid - 32) * 64; }
  int row = r0 + rr;
  int chunk = r0 >> 6;
  float v[64];
  float s = 0.f;
  if (row < M_) {
    const float4* p = (const float4*)(src + (size_t)row * C_ + c4 * 64);
#pragma unroll
    for (int i = 0; i < 16; ++i) {
      float4 q = p[i];
      v[i * 4 + 0] = q.x; v[i * 4 + 1] = q.y; v[i * 4 + 2] = q.z; v[i * 4 + 3] = q.w;
      s += q.x * q.x + q.y * q.y + q.z * q.z + q.w * q.w;
    }
  } else {
#pragma unroll
    for (int i = 0; i < 64; ++i) v[i] = 0.f;  // zero padding rows
  }
  s += __shfl_xor(s, 1, 64);
  s += __shfl_xor(s, 2, 64);
  float inv = (row < M_) ? 1.0f / fmaxf(sqrtf(s), NEPS) : 0.f;
#pragma unroll
  for (int i = 0; i < 16; ++i) {
    int c = c4 * 64 + i * 4;
    ushort4 o;
    o.x = f2bf(v[i * 4 + 0] * inv); o.y = f2bf(v[i * 4 + 1] * inv);
    o.z = f2bf(v[i * 4 + 2] * inv); o.w = f2bf(v[i * 4 + 3] * inv);
    int unit = (chunk * 32 + (c >> 5) * 4 + ((c >> 3) & 3)) * 64 + rr;
    *(ushort4*)&ms[(size_t)unit * 8 + (c & 7)] = o;
    *(ushort4*)&tile[rr][c] = o;
  }
  __syncthreads();
  int m = t & 63, cw = t >> 6;
#pragma unroll 8
  for (int j = 0; j < 64; ++j) {
    int c = cw * 64 + j;
    mt[(size_t)c * MP_ + r0 + m] = tile[m][c];
  }
}

// ---- fused per-pixel inv-norm + xnb bf16 [N,C] build (one feats pass) ----
__global__ __launch_bounds__(256) void prep_x_kernel(
    const float* __restrict__ feats, float* __restrict__ invn,
    unsigned short* __restrict__ xnb) {
  __shared__ unsigned short tileb[256][66];
  __shared__ float part[4][64];
  __shared__ float invs[64];
  int t = threadIdx.x, hwl = t & 63, cw = t >> 6;
  int n0 = blockIdx.x * 64;
  int b = n0 >> 12, hw0 = n0 & 4095;
  const float* p = feats + (size_t)b * C_ * HW_ + hw0 + hwl;
  float s = 0.f;
#pragma unroll 8
  for (int i = 0; i < 64; ++i) {
    int c = cw * 64 + i;
    float v = p[(size_t)c * HW_];
    s += v * v;
    tileb[c][hwl] = f2bf(v);
  }
  part[cw][hwl] = s;
  __syncthreads();
  if (t < 64) {
    float tot = part[0][t] + part[1][t] + part[2][t] + part[3][t];
    float inv = 1.0f / fmaxf(sqrtf(tot), NEPS);
    invn[n0 + t] = inv;
    invs[t] = inv;
  }
  __syncthreads();
  int px = t >> 2, q = t & 3;
  float iv = invs[px];
  unsigned short* xp = xnb + (size_t)(n0 + px) * C_;
#pragma unroll
  for (int blk = 0; blk < 8; ++blk) {
    int cb = blk * 4 + q;  // 4 q-lanes -> 64 B contiguous stores
    short8 o;
#pragma unroll
    for (int j = 0; j < 8; ++j)
      o[j] = (short)f2bf(bf2f(tileb[cb * 8 + j][px]) * iv);
    *(short8*)&xp[cb * 8] = o;
  }
}

// stage one 32 KB memS chunk into mtile (contiguous copy, no VGPR round-trip)
__device__ __forceinline__ void stage_chunk(const unsigned short* memS, int mc,
                                            unsigned short* mtile, int w, int l) {
  const unsigned short* src = memS + (size_t)mc * 16384;
#pragma unroll
  for (int it = 0; it < 4; ++it) {
    int seg = (it * 8 + w) * 512;  // u16 units; 64 lanes x 16 B = 1 KB/wave/iter
    async_copy16(src + seg + l * 8, mtile + seg);
  }
}

// ---------------- fused MFMA flash attention v9 ----------------
// = verified v4/v7 loop body (straight-line, branchless) + PEELED gate tail.
// v8 put the gate chunk inside the loop as an if/else -> two live code
// paths -> spill (FETCH 67->305MB, 2.3x slower). v9 keeps the loop body
// byte-identical to v7 (the prefetch even becomes unconditional: at mc=31
// it stages chunk 32 = W1^T), and runs the gate S-phase + finish ONCE after
// the loop, where its register demand (~92) can't perturb loop regalloc.
// Gate math/layout verified by v8's passing run (absmax 0.00195).
__global__ __launch_bounds__(512, 4) void flash_fused_kernel(
    const unsigned short* __restrict__ xnb,
    const unsigned short* __restrict__ fgS, const unsigned short* __restrict__ fgT,
    const unsigned short* __restrict__ bgS, const unsigned short* __restrict__ bgT,
    const float* __restrict__ feats, const float* __restrict__ invn,
    const float* __restrict__ b1fp, const float* __restrict__ w2fp,
    const float* __restrict__ b2fp, const float* __restrict__ b1bp,
    const float* __restrict__ w2bp, const float* __restrict__ b2bp,
    float* __restrict__ out) {
  __shared__ __align__(16) char smem[49920];
  unsigned short* mtile = (unsigned short*)smem;            // 32 KB frag-order chunk
  unsigned short* Pbuf0 = (unsigned short*)(smem + 32768);  // 8 KB: unit=(g*64+prow)
  unsigned short* Pbuf1 = (unsigned short*)(smem + 40960);  // 8 KB
  float* rowsum = (float*)(smem + 49152);                   // [64]
  float* comb   = (float*)(smem + 49408);                   // [64]
  float* gpart  = (float*)(smem + 49664);                   // [64] gate partials
  float* trans  = (float*)smem;                             // [64][67] f32, aliases mtile

  int t = threadIdx.x;
  int w = t >> 6, l = t & 63;
  int lm = l & 15, quad = l >> 4;
  int rg = w & 3, mh = w >> 2;
  int row0 = blockIdx.x * 64;

  // A-frags: rows row0 + 16*rg + lm (waves rg and rg+4 duplicate)
  short8 afrag[8];
  {
    const unsigned short* ap = xnb + (size_t)(row0 + 16 * rg + lm) * C_ + quad * 8;
#pragma unroll
    for (int kb = 0; kb < 8; ++kb)
      afrag[kb] = *(const short8*)(ap + kb * 32);
  }

  int bb = row0 >> 12, hw0 = row0 & 4095;
  float iv = invn[row0 + l];
  size_t ob = (size_t)bb * (size_t)C_ * HW_ + hw0 + l;

#pragma unroll 1
  for (int pass = 0; pass < 2; ++pass) {
    const unsigned short* memS  = pass ? bgS : fgS;
    const unsigned short* membT = pass ? bgT : fgT;

    floatx4 accO[4][2];
#pragma unroll
    for (int rt = 0; rt < 4; ++rt)
#pragma unroll
      for (int ct = 0; ct < 2; ++ct) accO[rt][ct] = (floatx4){0.f, 0.f, 0.f, 0.f};
    float rs[4] = {0.f, 0.f, 0.f, 0.f};
    if (t < 64) { rowsum[t] = 0.f; gpart[t] = 0.f; }  // ordered by chunk barriers

    stage_chunk(memS, 0, mtile, w, l);

#pragma unroll 1
    for (int mc = 0; mc < NCHUNK; ++mc) {
      __syncthreads();  // A: drains vmcnt -> mtile[mc] ready for all waves

      // PV B-frags for this chunk (global, read-once; hidden under S-phase)
      short8 bfT[2][2];
#pragma unroll
      for (int ct = 0; ct < 2; ++ct) {
        const unsigned short* tp =
            membT + (size_t)(w * 32 + ct * 16 + lm) * MP_ + mc * 64 + quad * 8;
        bfT[ct][0] = *(const short8*)(tp);
        bfT[ct][1] = *(const short8*)(tp + 32);
      }

      // ---- S = Q @ mem^T (rows 16rg.., m-half mh) from LDS frag-order tile ----
      floatx4 accS[2];
      accS[0] = (floatx4){0.f, 0.f, 0.f, 0.f};
      accS[1] = (floatx4){0.f, 0.f, 0.f, 0.f};
#pragma unroll
      for (int mt2 = 0; mt2 < 2; ++mt2) {
        int mrow = mh * 32 + mt2 * 16 + lm;
#pragma unroll
        for (int kb = 0; kb < 8; ++kb) {
          short8 bf = *(const short8*)&mtile[(size_t)(((kb * 4 + quad) * 64) + mrow) * 8];
          accS[mt2] = __builtin_amdgcn_mfma_f32_16x16x32_bf16(afrag[kb], bf, accS[mt2], 0, 0, 0);
        }
      }

      // ---- P = exp(S/T) bf16 (unnormalized; |logit|<=33.3), frag-order ----
      unsigned short* P = (mc & 1) ? Pbuf1 : Pbuf0;
#pragma unroll
      for (int mt2 = 0; mt2 < 2; ++mt2) {
        int m = mh * 32 + mt2 * 16 + lm;
        // exp-mask bias: padding rows get exp(-1e30) = 0 (no select);
        // valid rows: fma(S, IT, 0) == rn(S*IT) — bit-exact.
        float ebias = (mc * 64 + m < M_) ? 0.f : -1e30f;
        int g = mh * 4 + mt2 * 2 + (lm >> 3);
#pragma unroll
        for (int r = 0; r < 4; ++r) {
          float pv = __expf(__builtin_fmaf(accS[mt2][r], INV_TEMP, ebias));
          unsigned short pb = f2bf(pv);
          rs[r] += bf2f(pb);
          P[(g * 64 + 16 * rg + quad * 4 + r) * 8 + (lm & 7)] = pb;
        }
      }
      barrier_lds_only();  // B: P visible + mtile S-reads done (vmcnt alive)

      // issue next chunk's async stage (unconditional: mc=31 stages chunk 32
      // = W1^T for the peeled gate tail; in flight across PV)
      stage_chunk(memS, mc + 1, mtile, w, l);

      // ---- O += P @ mem (this wave's 32-wide C-slice) ----
#pragma unroll
      for (int rt = 0; rt < 4; ++rt) {
        short8 pf0 = *(const short8*)&P[(size_t)((0 + quad) * 64 + rt * 16 + lm) * 8];
        short8 pf1 = *(const short8*)&P[(size_t)((4 + quad) * 64 + rt * 16 + lm) * 8];
#pragma unroll
        for (int ct = 0; ct < 2; ++ct) {
          accO[rt][ct] = __builtin_amdgcn_mfma_f32_16x16x32_bf16(pf0, bfT[ct][0], accO[rt][ct], 0, 0, 0);
          accO[rt][ct] = __builtin_amdgcn_mfma_f32_16x16x32_bf16(pf1, bfT[ct][1], accO[rt][ct], 0, 0, 0);
        }
      }
    }

    // ---- peeled gate tail: h = xn @ W1 from the staged W1^T tile ----
    __syncthreads();  // drains vmcnt -> W1 tile ready
    {
      const float* b1p = pass ? b1bp : b1fp;
      const float* w2p = pass ? w2bp : w2fp;
      floatx4 accS[2];
      accS[0] = (floatx4){0.f, 0.f, 0.f, 0.f};
      accS[1] = (floatx4){0.f, 0.f, 0.f, 0.f};
#pragma unroll
      for (int mt2 = 0; mt2 < 2; ++mt2) {
        int mrow = mh * 32 + mt2 * 16 + lm;
#pragma unroll
        for (int kb = 0; kb < 8; ++kb) {
          short8 bf = *(const short8*)&mtile[(size_t)(((kb * 4 + quad) * 64) + mrow) * 8];
          accS[mt2] = __builtin_amdgcn_mfma_f32_16x16x32_bf16(afrag[kb], bf, accS[mt2], 0, 0, 0);
        }
      }
      // accS[mt2][r] = h[px=16rg+quad*4+r][hid=mh*32+mt2*16+lm]  (v8-verified)
      float b1a = b1p[mh * 32 + lm];
      float b1c = b1p[mh * 32 + 16 + lm];
      float w2a = w2p[mh * 32 + lm];
      float w2c = w2p[mh * 32 + 16 + lm];
      float p[4];
#pragma unroll
      for (int r = 0; r < 4; ++r)
        p[r] = fmaxf(accS[0][r] + b1a, 0.f) * w2a +
               fmaxf(accS[1][r] + b1c, 0.f) * w2c;
#pragma unroll
      for (int off = 1; off < 16; off <<= 1)
#pragma unroll
        for (int r = 0; r < 4; ++r) p[r] += __shfl_xor(p[r], off, 64);
      if (lm == 0) {
#pragma unroll
        for (int r = 0; r < 4; ++r)
          atomicAdd(&gpart[16 * rg + quad * 4 + r], p[r]);
      }
    }

    // ---- rowsum: intra-wave shuffle over lm, cross-wave LDS atomic ----
#pragma unroll
    for (int off = 1; off < 16; off <<= 1)
#pragma unroll
      for (int r = 0; r < 4; ++r) rs[r] += __shfl_xor(rs[r], off, 64);
    if (lm == 0) {
#pragma unroll
      for (int r = 0; r < 4; ++r) atomicAdd(&rowsum[16 * rg + quad * 4 + r], rs[r]);
    }
    __syncthreads();
    if (t < 64) {
      float b2v = (pass ? b2bp : b2fp)[0];
      float g = 1.f / (1.f + __expf(-(gpart[t] + b2v)));
      comb[t] = g / rowsum[t];
    }
    __syncthreads();

    // ---- epilogue (trans aliases mtile; gate reads + stages all drained) ----
#pragma unroll 1
    for (int cg2 = 0; cg2 < 4; ++cg2) {
      if ((w >> 1) == cg2) {
#pragma unroll
        for (int rt = 0; rt < 4; ++rt)
#pragma unroll
          for (int r = 0; r < 4; ++r) {
            float cf = comb[16 * rt + quad * 4 + r];
#pragma unroll
            for (int ct = 0; ct < 2; ++ct)
              trans[(16 * rt + quad * 4 + r) * 67 + (w & 1) * 32 + ct * 16 + lm] =
                  cf * accO[rt][ct][r];
          }
      }
      __syncthreads();
      if (pass == 0) {
#pragma unroll
        for (int i = 0; i < 8; ++i) {
          int cl = w * 8 + i;
          int cg = cg2 * 64 + cl;
          out[ob + (size_t)cg * HW_] = trans[l * 67 + cl];  // out = alpha_f * O_f
        }
      } else {
#pragma unroll
        for (int i = 0; i < 8; ++i) {
          int cl = w * 8 + i;
          int cg = cg2 * 64 + cl;
          size_t a = ob + (size_t)cg * HW_;
          out[a] = feats[a] * iv + out[a] - trans[l * 67 + cl];
        }
      }
      __syncthreads();
    }
  }
}

extern "C" void kernel_launch(void* const* d_in, const int* in_sizes, int n_in,
                              void* d_out, int out_size, void* d_ws, size_t ws_size,
                              hipStream_t stream) {
  const float* feats = (const float*)d_in[0];
  const float* fg    = (const float*)d_in[1];
  const float* bg    = (const float*)d_in[2];
  const float* w1f   = (const float*)d_in[3];
  const float* b1f   = (const float*)d_in[4];
  const float* w2f   = (const float*)d_in[5];
  const float* b2f   = (const float*)d_in[6];
  const float* w1b   = (const float*)d_in[7];
  const float* b1b   = (const float*)d_in[8];
  const float* w2b   = (const float*)d_in[9];
  const float* b2b   = (const float*)d_in[10];
  float* out = (float*)d_out;

  char* ws = (char*)d_ws;
  unsigned short* xnb = (unsigned short*)ws;                 // N_*C_ bf16
  unsigned short* fgS = xnb + (size_t)N_ * C_;               // (MP_+64)*C_ frag order
  unsigned short* bgS = fgS + (size_t)(MP_ + 64) * C_;       // (chunk 32 = W1^T)
  unsigned short* fgT = bgS + (size_t)(MP_ + 64) * C_;       // C_*MP_
  unsigned short* bgT = fgT + (size_t)C_ * MP_;
  float* invn = (float*)(bgT + (size_t)C_ * MP_);            // N_

  norm_mem_kernel<<<66, 256, 0, stream>>>(fg, bg, w1f, w1b, fgS, bgS, fgT, bgT);
  prep_x_kernel<<<N_ / 64, 256, 0, stream>>>(feats, invn, xnb);
  flash_fused_kernel<<<N_ / 64, 512, 0, stream>>>(
      xnb, fgS, fgT, bgS, bgT, feats, invn,
      b1f, w2f, b2f, b1b, w2b, b2b, out);
}

// Round 6
// 295.994 us; speedup vs baseline: 1.9864x; 1.0333x over previous
//
#include <hip/hip_runtime.h>
#include <math.h>

#define B_   8
#define C_   256
#define HW_  4096
#define N_   32768   // B_*HW_
#define M_   2024
#define MP_  2048    // M padded to multiple of 64
#define CH_  64
#define NCHUNK (MP_ / 64)  // 32 memory chunks; chunk 32 = W1^T (gate fusion)
#define INV_TEMP 33.333333333333336f
#define NEPS 1e-12f

typedef __attribute__((ext_vector_type(8))) short short8;   // 8 x bf16 (4 VGPRs)
typedef __attribute__((ext_vector_type(4))) float floatx4;  // MFMA accumulator

__device__ __forceinline__ unsigned short f2bf(float f) {
  union { float f; unsigned u; } v; v.f = f;
  unsigned r = v.u + 0x7FFFu + ((v.u >> 16) & 1u);  // RNE, finite inputs only
  return (unsigned short)(r >> 16);
}
__device__ __forceinline__ float bf2f(unsigned short b) {
  union { unsigned u; float f; } v; v.u = ((unsigned)b) << 16; return v.f;
}

// raw workgroup barrier that does NOT drain vmcnt (keeps global_load_lds
// prefetch in flight across it) — CK/AITER idiom.
__device__ __forceinline__ void barrier_lds_only() {
  asm volatile("s_waitcnt lgkmcnt(0)\n\ts_barrier" ::: "memory");
}

// async 16B/lane global->LDS copy; LDS dest = wave-uniform base + lane*16.
__device__ __forceinline__ void async_copy16(const unsigned short* gsrc,
                                             unsigned short* lds) {
  __builtin_amdgcn_global_load_lds(
      (const __attribute__((address_space(1))) void*)gsrc,
      (__attribute__((address_space(3))) void*)lds, 16, 0, 0);
}

// ---- normalize memory rows -> memS (MFMA B-frag order) + membT [C][MP] ----
// memS element (m, c): unit = ((m>>6)*32 + (c>>5)*4 + ((c>>3)&3))*64 + (m&63),
// u16 index = unit*8 + (c&7). A 64-row chunk is a contiguous 32 KB block that
// the flash kernel copies to LDS verbatim via global_load_lds.
// Blocks 64/65: pack W1^T (row h = w1[:,h], bf16, no normalize) as chunk 32
// of fgS/bgS — the flash kernel computes the gate hidden layer as a peeled
// extra S-phase pass (gate_kernel eliminated).
__global__ __launch_bounds__(256) void norm_mem_kernel(
    const float* __restrict__ fg, const float* __restrict__ bg,
    const float* __restrict__ w1f, const float* __restrict__ w1b,
    unsigned short* __restrict__ fgS, unsigned short* __restrict__ bgS,
    unsigned short* __restrict__ fgT, unsigned short* __restrict__ bgT) {
  __shared__ unsigned short tile[64][258];
  int bid = blockIdx.x;  // 0..31 fg chunks, 32..63 bg chunks, 64/65 w1 chunks
  int t = threadIdx.x;
  int rr = t >> 2, c4 = t & 3;  // row rr, channel quarter c4

  if (bid >= 64) {  // W1^T chunk (64 rows h, 256 cols c), chunk index 32
    const float* srcw = (bid == 64) ? w1f : w1b;
    unsigned short* ms = (bid == 64) ? fgS : bgS;
#pragma unroll
    for (int i = 0; i < 16; ++i) {
      int c = c4 * 64 + i * 4;
      ushort4 o;
      o.x = f2bf(srcw[(size_t)(c + 0) * CH_ + rr]);
      o.y = f2bf(srcw[(size_t)(c + 1) * CH_ + rr]);
      o.z = f2bf(srcw[(size_t)(c + 2) * CH_ + rr]);
      o.w = f2bf(srcw[(size_t)(c + 3) * CH_ + rr]);
      int unit = (32 * 32 + (c >> 5) * 4 + ((c >> 3) & 3)) * 64 + rr;
      *(ushort4*)&ms[(size_t)unit * 8 + (c & 7)] = o;
    }
    return;  // whole block exits (no __syncthreads reached)
  }

  const float* src; unsigned short *ms, *mt; int r0;
  if (bid < 32) { src = fg; ms = fgS; mt = fgT; r0 = bid * 64; }
  else          { src = bg; ms = bgS; mt = bgT; r0 = (bid - 32) * 64; }
  int row = r0 + rr;
  int chunk = r0 >> 6;
  float v[64];
  float s = 0.f;
  if (row < M_) {
    const float4* p = (const float4*)(src + (size_t)row * C_ + c4 * 64);
#pragma unroll
    for (int i = 0; i < 16; ++i) {
      float4 q = p[i];
      v[i * 4 + 0] = q.x; v[i * 4 + 1] = q.y; v[i * 4 + 2] = q.z; v[i * 4 + 3] = q.w;
      s += q.x * q.x + q.y * q.y + q.z * q.z + q.w * q.w;
    }
  } else {
#pragma unroll
    for (int i = 0; i < 64; ++i) v[i] = 0.f;  // zero padding rows
  }
  s += __shfl_xor(s, 1, 64);
  s += __shfl_xor(s, 2, 64);
  float inv = (row < M_) ? 1.0f / fmaxf(sqrtf(s), NEPS) : 0.f;
#pragma unroll
  for (int i = 0; i < 16; ++i) {
    int c = c4 * 64 + i * 4;
    ushort4 o;
    o.x = f2bf(v[i * 4 + 0] * inv); o.y = f2bf(v[i * 4 + 1] * inv);
    o.z = f2bf(v[i * 4 + 2] * inv); o.w = f2bf(v[i * 4 + 3] * inv);
    int unit = (chunk * 32 + (c >> 5) * 4 + ((c >> 3) & 3)) * 64 + rr;
    *(ushort4*)&ms[(size_t)unit * 8 + (c & 7)] = o;
    *(ushort4*)&tile[rr][c] = o;
  }
  __syncthreads();
  int m = t & 63, cw = t >> 6;
#pragma unroll 8
  for (int j = 0; j < 64; ++j) {
    int c = cw * 64 + j;
    mt[(size_t)c * MP_ + r0 + m] = tile[m][c];
  }
}

// stage one 32 KB memS chunk into mtile (contiguous copy, no VGPR round-trip)
__device__ __forceinline__ void stage_chunk(const unsigned short* memS, int mc,
                                            unsigned short* mtile, int w, int l) {
  const unsigned short* src = memS + (size_t)mc * 16384;
#pragma unroll
  for (int it = 0; it < 4; ++it) {
    int seg = (it * 8 + w) * 512;  // u16 units; 64 lanes x 16 B = 1 KB/wave/iter
    async_copy16(src + seg + l * 8, mtile + seg);
  }
}

// ---------------- fused MFMA flash attention v10 ----------------
// = v9 (verified: straight-line loop + peeled gate tail) + prep_x fusion.
// Since the gate is fused, each block's 64 pixel rows are the ONLY consumer
// of xnb/invn -> build them in a prologue from feats directly: lane=pixel,
// wave=32-channel slice, LDS reduce for ||x||, bf16 xn tile [64][264] in LDS
// (aliases mtile pre-staging), afrag read from LDS, barrier, then the v9
// body unchanged. Eliminates the prep_x dispatch and the xnb/invn global
// round-trips. xn rounds ONCE (f2bf(v*iv) from f32) vs prep_x's double
// rounding. All new code sits outside the hot loop (v8->v9 spill lesson).
__global__ __launch_bounds__(512, 4) void flash_fused_kernel(
    const unsigned short* __restrict__ fgS, const unsigned short* __restrict__ fgT,
    const unsigned short* __restrict__ bgS, const unsigned short* __restrict__ bgT,
    const float* __restrict__ feats,
    const float* __restrict__ b1fp, const float* __restrict__ w2fp,
    const float* __restrict__ b2fp, const float* __restrict__ b1bp,
    const float* __restrict__ w2bp, const float* __restrict__ b2bp,
    float* __restrict__ out) {
  __shared__ __align__(16) char smem[49920];
  unsigned short* mtile = (unsigned short*)smem;            // 32 KB frag-order chunk
  unsigned short* Pbuf0 = (unsigned short*)(smem + 32768);  // 8 KB: unit=(g*64+prow)
  unsigned short* Pbuf1 = (unsigned short*)(smem + 40960);  // 8 KB
  float* rowsum = (float*)(smem + 49152);                   // [64]
  float* comb   = (float*)(smem + 49408);                   // [64]
  float* gpart  = (float*)(smem + 49664);                   // [64] gate partials
  float* trans  = (float*)smem;                             // [64][67] f32, aliases mtile
  // prologue-only aliases (die before first P-write / stage):
  unsigned short* xtile = (unsigned short*)smem;            // [64][264] u16, 33792 B
  float* part = (float*)(smem + 33792);                     // [8][64]
  float* invs = (float*)(smem + 35840);                     // [64]

  int t = threadIdx.x;
  int w = t >> 6, l = t & 63;
  int lm = l & 15, quad = l >> 4;
  int rg = w & 3, mh = w >> 2;
  int row0 = blockIdx.x * 64;
  int bb = row0 >> 12, hw0 = row0 & 4095;
  size_t ob = (size_t)bb * (size_t)C_ * HW_ + hw0 + l;

  // ---- fused prep_x prologue: xn tile + invn from feats (this block only) ----
  float iv;
  short8 afrag[8];
  {
    const float* p = feats + (size_t)bb * C_ * HW_ + hw0 + l;  // lane l = pixel
    float vv[32];
    float s = 0.f;
#pragma unroll
    for (int i = 0; i < 32; ++i) {
      float v = p[(size_t)(w * 32 + i) * HW_];
      vv[i] = v;
      s += v * v;
    }
    part[w * 64 + l] = s;
    __syncthreads();
    if (t < 64) {
      float tot = 0.f;
#pragma unroll
      for (int j = 0; j < 8; ++j) tot += part[j * 64 + t];
      invs[t] = 1.0f / fmaxf(sqrtf(tot), NEPS);
    }
    __syncthreads();
    float ivl = invs[l];
    unsigned short* xr = xtile + l * 264 + w * 32;  // row stride 264 -> 16B-aligned
#pragma unroll
    for (int i = 0; i < 32; i += 8) {
      short8 o;
#pragma unroll
      for (int j = 0; j < 8; ++j) o[j] = (short)f2bf(vv[i + j] * ivl);
      *(short8*)&xr[i] = o;
    }
    __syncthreads();
    iv = invs[l];
    // A-frags: row px=16rg+lm, cols quad*8 + kb*32 (waves rg and rg+4 duplicate)
    const unsigned short* xb = xtile + (16 * rg + lm) * 264 + quad * 8;
#pragma unroll
    for (int kb = 0; kb < 8; ++kb)
      afrag[kb] = *(const short8*)(xb + kb * 32);
    __syncthreads();  // afrag ds_reads drained before staging overwrites xtile
  }

#pragma unroll 1
  for (int pass = 0; pass < 2; ++pass) {
    const unsigned short* memS  = pass ? bgS : fgS;
    const unsigned short* membT = pass ? bgT : fgT;

    floatx4 accO[4][2];
#pragma unroll
    for (int rt = 0; rt < 4; ++rt)
#pragma unroll
      for (int ct = 0; ct < 2; ++ct) accO[rt][ct] = (floatx4){0.f, 0.f, 0.f, 0.f};
    float rs[4] = {0.f, 0.f, 0.f, 0.f};
    if (t < 64) { rowsum[t] = 0.f; gpart[t] = 0.f; }  // ordered by chunk barriers

    stage_chunk(memS, 0, mtile, w, l);

#pragma unroll 1
    for (int mc = 0; mc < NCHUNK; ++mc) {
      __syncthreads();  // A: drains vmcnt -> mtile[mc] ready for all waves

      // PV B-frags for this chunk (global, read-once; hidden under S-phase)
      short8 bfT[2][2];
#pragma unroll
      for (int ct = 0; ct < 2; ++ct) {
        const unsigned short* tp =
            membT + (size_t)(w * 32 + ct * 16 + lm) * MP_ + mc * 64 + quad * 8;
        bfT[ct][0] = *(const short8*)(tp);
        bfT[ct][1] = *(const short8*)(tp + 32);
      }

      // ---- S = Q @ mem^T (rows 16rg.., m-half mh) from LDS frag-order tile ----
      floatx4 accS[2];
      accS[0] = (floatx4){0.f, 0.f, 0.f, 0.f};
      accS[1] = (floatx4){0.f, 0.f, 0.f, 0.f};
#pragma unroll
      for (int mt2 = 0; mt2 < 2; ++mt2) {
        int mrow = mh * 32 + mt2 * 16 + lm;
#pragma unroll
        for (int kb = 0; kb < 8; ++kb) {
          short8 bf = *(const short8*)&mtile[(size_t)(((kb * 4 + quad) * 64) + mrow) * 8];
          accS[mt2] = __builtin_amdgcn_mfma_f32_16x16x32_bf16(afrag[kb], bf, accS[mt2], 0, 0, 0);
        }
      }

      // ---- P = exp(S/T) bf16 (unnormalized; |logit|<=33.3), frag-order ----
      unsigned short* P = (mc & 1) ? Pbuf1 : Pbuf0;
#pragma unroll
      for (int mt2 = 0; mt2 < 2; ++mt2) {
        int m = mh * 32 + mt2 * 16 + lm;
        // exp-mask bias: padding rows get exp(-1e30) = 0 (no select);
        // valid rows: fma(S, IT, 0) == rn(S*IT) — bit-exact.
        float ebias = (mc * 64 + m < M_) ? 0.f : -1e30f;
        int g = mh * 4 + mt2 * 2 + (lm >> 3);
#pragma unroll
        for (int r = 0; r < 4; ++r) {
          float pv = __expf(__builtin_fmaf(accS[mt2][r], INV_TEMP, ebias));
          unsigned short pb = f2bf(pv);
          rs[r] += bf2f(pb);
          P[(g * 64 + 16 * rg + quad * 4 + r) * 8 + (lm & 7)] = pb;
        }
      }
      barrier_lds_only();  // B: P visible + mtile S-reads done (vmcnt alive)

      // issue next chunk's async stage (unconditional: mc=31 stages chunk 32
      // = W1^T for the peeled gate tail; in flight across PV)
      stage_chunk(memS, mc + 1, mtile, w, l);

      // ---- O += P @ mem (this wave's 32-wide C-slice) ----
#pragma unroll
      for (int rt = 0; rt < 4; ++rt) {
        short8 pf0 = *(const short8*)&P[(size_t)((0 + quad) * 64 + rt * 16 + lm) * 8];
        short8 pf1 = *(const short8*)&P[(size_t)((4 + quad) * 64 + rt * 16 + lm) * 8];
#pragma unroll
        for (int ct = 0; ct < 2; ++ct) {
          accO[rt][ct] = __builtin_amdgcn_mfma_f32_16x16x32_bf16(pf0, bfT[ct][0], accO[rt][ct], 0, 0, 0);
          accO[rt][ct] = __builtin_amdgcn_mfma_f32_16x16x32_bf16(pf1, bfT[ct][1], accO[rt][ct], 0, 0, 0);
        }
      }
    }

    // ---- peeled gate tail: h = xn @ W1 from the staged W1^T tile ----
    __syncthreads();  // drains vmcnt -> W1 tile ready
    {
      const float* b1p = pass ? b1bp : b1fp;
      const float* w2p = pass ? w2bp : w2fp;
      floatx4 accS[2];
      accS[0] = (floatx4){0.f, 0.f, 0.f, 0.f};
      accS[1] = (floatx4){0.f, 0.f, 0.f, 0.f};
#pragma unroll
      for (int mt2 = 0; mt2 < 2; ++mt2) {
        int mrow = mh * 32 + mt2 * 16 + lm;
#pragma unroll
        for (int kb = 0; kb < 8; ++kb) {
          short8 bf = *(const short8*)&mtile[(size_t)(((kb * 4 + quad) * 64) + mrow) * 8];
          accS[mt2] = __builtin_amdgcn_mfma_f32_16x16x32_bf16(afrag[kb], bf, accS[mt2], 0, 0, 0);
        }
      }
      // accS[mt2][r] = h[px=16rg+quad*4+r][hid=mh*32+mt2*16+lm]  (v8-verified)
      float b1a = b1p[mh * 32 + lm];
      float b1c = b1p[mh * 32 + 16 + lm];
      float w2a = w2p[mh * 32 + lm];
      float w2c = w2p[mh * 32 + 16 + lm];
      float p[4];
#pragma unroll
      for (int r = 0; r < 4; ++r)
        p[r] = fmaxf(accS[0][r] + b1a, 0.f) * w2a +
               fmaxf(accS[1][r] + b1c, 0.f) * w2c;
#pragma unroll
      for (int off = 1; off < 16; off <<= 1)
#pragma unroll
        for (int r = 0; r < 4; ++r) p[r] += __shfl_xor(p[r], off, 64);
      if (lm == 0) {
#pragma unroll
        for (int r = 0; r < 4; ++r)
          atomicAdd(&gpart[16 * rg + quad * 4 + r], p[r]);
      }
    }

    // ---- rowsum: intra-wave shuffle over lm, cross-wave LDS atomic ----
#pragma unroll
    for (int off = 1; off < 16; off <<= 1)
#pragma unroll
      for (int r = 0; r < 4; ++r) rs[r] += __shfl_xor(rs[r], off, 64);
    if (lm == 0) {
#pragma unroll
      for (int r = 0; r < 4; ++r) atomicAdd(&rowsum[16 * rg + quad * 4 + r], rs[r]);
    }
    __syncthreads();
    if (t < 64) {
      float b2v = (pass ? b2bp : b2fp)[0];
      float g = 1.f / (1.f + __expf(-(gpart[t] + b2v)));
      comb[t] = g / rowsum[t];
    }
    __syncthreads();

    // ---- epilogue (trans aliases mtile; gate reads + stages all drained) ----
#pragma unroll 1
    for (int cg2 = 0; cg2 < 4; ++cg2) {
      if ((w >> 1) == cg2) {
#pragma unroll
        for (int rt = 0; rt < 4; ++rt)
#pragma unroll
          for (int r = 0; r < 4; ++r) {
            float cf = comb[16 * rt + quad * 4 + r];
#pragma unroll
            for (int ct = 0; ct < 2; ++ct)
              trans[(16 * rt + quad * 4 + r) * 67 + (w & 1) * 32 + ct * 16 + lm] =
                  cf * accO[rt][ct][r];
          }
      }
      __syncthreads();
      if (pass == 0) {
#pragma unroll
        for (int i = 0; i < 8; ++i) {
          int cl = w * 8 + i;
          int cg = cg2 * 64 + cl;
          out[ob + (size_t)cg * HW_] = trans[l * 67 + cl];  // out = alpha_f * O_f
        }
      } else {
#pragma unroll
        for (int i = 0; i < 8; ++i) {
          int cl = w * 8 + i;
          int cg = cg2 * 64 + cl;
          size_t a = ob + (size_t)cg * HW_;
          out[a] = feats[a] * iv + out[a] - trans[l * 67 + cl];
        }
      }
      __syncthreads();
    }
  }
}

extern "C" void kernel_launch(void* const* d_in, const int* in_sizes, int n_in,
                              void* d_out, int out_size, void* d_ws, size_t ws_size,
                              hipStream_t stream) {
  const float* feats = (const float*)d_in[0];
  const float* fg    = (const float*)d_in[1];
  const float* bg    = (const float*)d_in[2];
  const float* w1f   = (const float*)d_in[3];
  const float* b1f   = (const float*)d_in[4];
  const float* w2f   = (const float*)d_in[5];
  const float* b2f   = (const float*)d_in[6];
  const float* w1b   = (const float*)d_in[7];
  const float* b1b   = (const float*)d_in[8];
  const float* w2b   = (const float*)d_in[9];
  const float* b2b   = (const float*)d_in[10];
  float* out = (float*)d_out;

  char* ws = (char*)d_ws;
  unsigned short* fgS = (unsigned short*)ws;                 // (MP_+64)*C_ frag order
  unsigned short* bgS = fgS + (size_t)(MP_ + 64) * C_;       // (chunk 32 = W1^T)
  unsigned short* fgT = bgS + (size_t)(MP_ + 64) * C_;       // C_*MP_
  unsigned short* bgT = fgT + (size_t)C_ * MP_;

  norm_mem_kernel<<<66, 256, 0, stream>>>(fg, bg, w1f, w1b, fgS, bgS, fgT, bgT);
  flash_fused_kernel<<<N_ / 64, 512, 0, stream>>>(
      fgS, fgT, bgS, bgT, feats,
      b1f, w2f, b2f, b1b, w2b, b2b, out);
}